// Round 14
// baseline (1725.629 us; speedup 1.0000x reference)
//
#include <hip/hip_runtime.h>
#include <hip/hip_bf16.h>

#define TT 8192      // tokens
#define DD 1024
#define EE 8
#define HH 4096
#define SLOTS 16384  // TT * K
#define SLOTSP (SLOTS + 256)
#define MAXRT2 (SLOTS / 256 + EE)  // 72 worst-case 256-row tiles
#define NRB 2048                   // router blocks (4 tokens each)
#define NWB 2048                   // wconv blocks (grid-stride)

typedef __bf16 bf16x8 __attribute__((ext_vector_type(8)));
typedef float f32x4 __attribute__((ext_vector_type(4)));

__device__ __forceinline__ float bf2f(unsigned u) { return __uint_as_float(u << 16); }
__device__ __forceinline__ unsigned short f2bf(float f) {
  __hip_bfloat16 h = __float2bfloat16(f);
  return __builtin_bit_cast(unsigned short, h);
}
__device__ __forceinline__ f32x4 MF(bf16x8 a, bf16x8 b, f32x4 c) {
  return __builtin_amdgcn_mfma_f32_16x16x32_bf16(a, b, c, 0, 0, 0);
}

// ctrl layout (ints): [0..7]=cnt  [8..16]=off  [25..33]=rtp (256-row tiles)

// ============ fused: router (blocks 0..NRB-1, 4 tok/blk, NO atomics) ============
// ============         + weight fp32->bf16 (blocks NRB..NRB+NWB-1)    ============
__global__ __launch_bounds__(256) void k_fused_rw(
    const float* __restrict__ x, const float* __restrict__ rls,
    const float* __restrict__ rlb, const float* __restrict__ rw,
    const float* __restrict__ rb, const float* __restrict__ w1,
    const float* __restrict__ w2, unsigned short* __restrict__ xhat,
    int* __restrict__ topk, float* __restrict__ gates, int* __restrict__ ranks,
    int* __restrict__ blkcnt, unsigned short* __restrict__ w1b,
    unsigned short* __restrict__ w2b) {
  if (blockIdx.x >= NRB) {
    const size_t n4t = (size_t)2 * EE * HH * DD / 4;
    const size_t n4w1 = (size_t)EE * HH * DD / 4;
    size_t i = (size_t)(blockIdx.x - NRB) * 256 + threadIdx.x;
    const size_t stride = (size_t)NWB * 256;
    for (; i < n4t; i += stride) {
      const float4* src; unsigned short* dst; size_t j;
      if (i < n4w1) { src = (const float4*)w1; dst = w1b; j = i; }
      else          { src = (const float4*)w2; dst = w2b; j = i - n4w1; }
      float4 v = src[j];
      ushort4 ov;
      ov.x = f2bf(v.x); ov.y = f2bf(v.y); ov.z = f2bf(v.z); ov.w = f2bf(v.w);
      ((ushort4*)dst)[j] = ov;
    }
    return;
  }
  const int tid = threadIdx.x, lane = tid & 63, v = tid >> 6;
  const int t = blockIdx.x * 4 + v;
  __shared__ int sh_e[4][2];
  const float4* xr = (const float4*)(x + (size_t)t * DD);
  float4 xv[4];
#pragma unroll
  for (int j = 0; j < 4; ++j) xv[j] = xr[lane + 64 * j];
  float s = 0.f, s2 = 0.f;
#pragma unroll
  for (int j = 0; j < 4; ++j) {
    s += xv[j].x + xv[j].y + xv[j].z + xv[j].w;
    s2 += xv[j].x * xv[j].x + xv[j].y * xv[j].y + xv[j].z * xv[j].z + xv[j].w * xv[j].w;
  }
#pragma unroll
  for (int o = 32; o > 0; o >>= 1) { s += __shfl_xor(s, o); s2 += __shfl_xor(s2, o); }
  const float mean = s * (1.0f / DD);
  const float var = s2 * (1.0f / DD) - mean * mean;
  const float inv = rsqrtf(var + 1e-6f);
  float xh[4][4];
  unsigned short* xo = xhat + (size_t)t * DD;
#pragma unroll
  for (int j = 0; j < 4; ++j) {
    xh[j][0] = (xv[j].x - mean) * inv; xh[j][1] = (xv[j].y - mean) * inv;
    xh[j][2] = (xv[j].z - mean) * inv; xh[j][3] = (xv[j].w - mean) * inv;
    ushort4 pk;
    pk.x = f2bf(xh[j][0]); pk.y = f2bf(xh[j][1]);
    pk.z = f2bf(xh[j][2]); pk.w = f2bf(xh[j][3]);
    ((ushort4*)xo)[lane + 64 * j] = pk;
  }
  float r[4][4];
#pragma unroll
  for (int j = 0; j < 4; ++j) {
    float4 sc = ((const float4*)rls)[lane + 64 * j];
    float4 bi = ((const float4*)rlb)[lane + 64 * j];
    r[j][0] = fmaf(xh[j][0], sc.x, bi.x); r[j][1] = fmaf(xh[j][1], sc.y, bi.y);
    r[j][2] = fmaf(xh[j][2], sc.z, bi.z); r[j][3] = fmaf(xh[j][3], sc.w, bi.w);
  }
  float pe[EE];
#pragma unroll
  for (int e = 0; e < EE; ++e) {
    float acc = 0.f;
#pragma unroll
    for (int j = 0; j < 4; ++j) {
      float4 w = ((const float4*)(rw + (size_t)e * DD))[lane + 64 * j];
      acc = fmaf(r[j][0], w.x, fmaf(r[j][1], w.y, fmaf(r[j][2], w.z, fmaf(r[j][3], w.w, acc))));
    }
    pe[e] = acc;
  }
#pragma unroll
  for (int o = 32; o > 0; o >>= 1) {
#pragma unroll
    for (int e = 0; e < EE; ++e) pe[e] += __shfl_xor(pe[e], o);
  }
  int i1 = 0, i2 = -1;
  if (lane == 0) {
    float lg[EE];
    for (int e = 0; e < EE; ++e) lg[e] = pe[e] + rb[e];
    for (int e = 1; e < EE; ++e) if (lg[e] > lg[i1]) i1 = e;
    for (int e = 0; e < EE; ++e) { if (e == i1) continue; if (i2 < 0 || lg[e] > lg[i2]) i2 = e; }
    float eb = expf(lg[i2] - lg[i1]);
    float den = 1.0f / (1.0f + eb);
    topk[t] = i1 | (i2 << 8);
    gates[2 * t] = den;
    gates[2 * t + 1] = eb * den;
    sh_e[v][0] = i1; sh_e[v][1] = i2;
  }
  __syncthreads();
  if (lane == 0) {
    int r0 = 0, r1 = 0;
    for (int q = 0; q < 2 * v; ++q) {
      int ee = sh_e[q >> 1][q & 1];
      r0 += (ee == i1); r1 += (ee == i2);
    }
    ranks[2 * t] = r0;
    ranks[2 * t + 1] = r1;
  }
  if (tid < EE) {
    int c = 0;
    for (int q = 0; q < 8; ++q) c += (sh_e[q >> 1][q & 1] == tid);
    blkcnt[blockIdx.x * EE + tid] = c;
  }
}

// ---- offsets: two-level scan over blkcnt[NRB][8] -> per-block bases + ctrl ----
__global__ __launch_bounds__(256) void k_offsets(int* __restrict__ ctrl,
                                                 int* __restrict__ blkcnt) {
  __shared__ int chunk[32 * EE];
  __shared__ int tot[EE];
  const int t = threadIdx.x, e = t & 7, c = t >> 3;
  int s = 0;
  for (int i = 0; i < 64; ++i) s += blkcnt[(c * 64 + i) * EE + e];
  chunk[c * EE + e] = s;
  __syncthreads();
  if (t < EE) {
    int run = 0;
    for (int c2 = 0; c2 < 32; ++c2) { int vv = chunk[c2 * EE + t]; chunk[c2 * EE + t] = run; run += vv; }
    tot[t] = run;
    ctrl[t] = run;
  }
  __syncthreads();
  if (t == 0) {
    int o = 0, rr = 0;
    ctrl[8] = 0; ctrl[25] = 0;
    for (int e2 = 0; e2 < EE; ++e2) {
      int cc = tot[e2];
      o += cc; ctrl[9 + e2] = o;
      rr += (cc + 255) >> 8; ctrl[26 + e2] = rr;   // 256-row tiles
    }
  }
  int run = chunk[c * EE + e];
  for (int i = 0; i < 64; ++i) {
    int idx = (c * 64 + i) * EE + e;
    int vv = blkcnt[idx];
    blkcnt[idx] = run;
    run += vv;
  }
}

// ---- build A rows (expert LN applied to xhat); pos from scan, no atomics ----
__global__ __launch_bounds__(256) void k_build(
    const unsigned short* __restrict__ xhat, const float* __restrict__ els,
    const float* __restrict__ elb, const int* __restrict__ ctrl,
    const int* __restrict__ topk, const int* __restrict__ ranks,
    const int* __restrict__ blkbase, unsigned short* __restrict__ A,
    int* __restrict__ tok_pos) {
  int p = blockIdx.x * 2 + (threadIdx.x >> 7);
  int t = p >> 1, k = p & 1, tid = threadIdx.x & 127;
  int e = (topk[t] >> (k * 8)) & 0xff;
  int pos = ctrl[8 + e] + blkbase[(p >> 3) * EE + e] + ranks[p];
  if (tid == 0) tok_pos[p] = pos;
  int i = tid * 8;
  uint4 xv = *(const uint4*)(xhat + (size_t)t * DD + i);
  const float* sp = els + (size_t)e * DD + i;
  const float* bp = elb + (size_t)e * DD + i;
  float4 s0 = *(const float4*)sp, s1 = *(const float4*)(sp + 4);
  float4 b0 = *(const float4*)bp, b1 = *(const float4*)(bp + 4);
  unsigned r0 = (unsigned)f2bf(fmaf(bf2f(xv.x & 0xffffu), s0.x, b0.x)) |
                ((unsigned)f2bf(fmaf(bf2f(xv.x >> 16), s0.y, b0.y)) << 16);
  unsigned r1 = (unsigned)f2bf(fmaf(bf2f(xv.y & 0xffffu), s0.z, b0.z)) |
                ((unsigned)f2bf(fmaf(bf2f(xv.y >> 16), s0.w, b0.w)) << 16);
  unsigned r2 = (unsigned)f2bf(fmaf(bf2f(xv.z & 0xffffu), s1.x, b1.x)) |
                ((unsigned)f2bf(fmaf(bf2f(xv.z >> 16), s1.y, b1.y)) << 16);
  unsigned r3 = (unsigned)f2bf(fmaf(bf2f(xv.w & 0xffffu), s1.z, b1.z)) |
                ((unsigned)f2bf(fmaf(bf2f(xv.w >> 16), s1.w, b1.w)) << 16);
  uint4 ov; ov.x = r0; ov.y = r1; ov.z = r2; ov.w = r3;
  *(uint4*)(A + (size_t)pos * DD + i) = ov;
}

// == grouped GEMM, BM=256 x BN=128, BK=32, 512thr/8 waves, 24 waves/CU (R14) ==
// Per-wave output 64x64 (acc[4][4], ~52 VGPR) — SAME per-wave mix as R11;
// block doubles (8 waves, 4M x 2N) so 3 blocks/CU = 6 waves/SIMD (vs 3).
// LDS: buf p at p*24576: A 256x32 (16KB, 16 subtiles) + B 128x32 (8KB).
// st_16x32 swizzle both-sides (rule #21). Loop = R8 unpinned 2-phase:
// STAGE(p^1) -> 8 ds_read -> 16 MFMA -> __syncthreads.
// Block order: bijective XCD swizzle + A-panel-major (R6/R11 win).
#define GLL(S, D)                                                              \
  __builtin_amdgcn_global_load_lds(                                            \
      (const __attribute__((address_space(1))) unsigned int*)(S),              \
      (__attribute__((address_space(3))) unsigned int*)(D), 16, 0, 0)
// wave w stages A subtiles {2w,2w+1} (rows 32w+ri, 32w+16+ri) + B subtile {w}
#define STAGE(P, KT) do {                                                      \
    const unsigned short* sA_ = pA + (size_t)(KT) * 32;                        \
    const unsigned short* sB_ = pB + (size_t)(KT) * 32;                        \
    char* dA_ = sLA + (P) * 24576;                                             \
    char* dB_ = sLB + (P) * 24576;                                             \
    GLL(sA_, dA_); GLL(sA_ + 16 * KDIM, dA_ + 1024);                           \
    GLL(sB_, dB_);                                                             \
  } while (0)

template <int KDIM, bool GELU>
__global__ __launch_bounds__(512, 6) void k_gemm6(
    const unsigned short* __restrict__ Amat,  // [SLOTSP][KDIM] bf16
    const unsigned short* __restrict__ W,     // [EE][NTOT][KDIM] bf16
    const float* __restrict__ bias,           // [EE][NTOT]
    unsigned short* __restrict__ Outm,        // [SLOTSP][NTOT] bf16
    const int* __restrict__ ctrl, int NTOT) {
  constexpr int NT = KDIM / 32;
  __shared__ __align__(16) char smem[49152];
  const int* rtp = ctrl + 25;

  // bijective XCD swizzle (m204) + A-panel-major order (R11 config)
  const int nwg = gridDim.x * gridDim.y;
  const int lin = blockIdx.y * gridDim.x + blockIdx.x;
  const int xcd = lin & 7, loc = lin >> 3;
  const int q = nwg >> 3, rr = nwg & 7;
  const int lin2 = (xcd < rr ? xcd * (q + 1) : rr * (q + 1) + (xcd - rr) * q) + loc;
  const int by = lin2 % gridDim.y;
  const int bx = lin2 / gridDim.y;
  if (bx >= rtp[EE]) return;
  int e = 0;
  while (bx >= rtp[e + 1]) ++e;
  const int rt = bx - rtp[e];
  const int row0 = ctrl[8 + e] + rt * 256;
  int vrows = ctrl[e] - rt * 256;
  if (vrows > 256) vrows = 256;
  const int n0 = by * 128;

  const int tid = threadIdx.x, lane = tid & 63, w = tid >> 6;
  const int wr = w >> 1, wc = w & 1;  // 4M x 2N waves; per-wave out 64x64

  // staging lane geometry (inverse swizzle on the global source)
  const int u = (lane * 16) ^ (((lane >> 5) & 1) << 5);
  const int ri = u >> 6;         // in-subtile row 0..15
  const int ci = (u & 63) >> 1;  // in-subtile col elem 0/8/16/24
  const unsigned short* pA = Amat + (size_t)(row0 + 32 * w + ri) * KDIM + ci;
  const unsigned short* pB = W + ((size_t)e * NTOT + n0 + 16 * w + ri) * KDIM + ci;
  char* sLA = smem + (2 * w) * 1024 + lane * 16;          // A subtiles 2w,2w+1
  char* sLB = smem + 16384 + w * 1024 + lane * 16;        // B subtile w

  // fragment-read lane term (swizzled): row=lane&15, col byte=(lane>>4)*16
  const int lt = (((lane & 15) << 6) | ((lane >> 4) << 4)) ^ (((lane >> 3) & 1) << 5);

  f32x4 acc[4][4];
#pragma unroll
  for (int m = 0; m < 4; ++m)
#pragma unroll
    for (int n = 0; n < 4; ++n) acc[m][n] = (f32x4){0.f, 0.f, 0.f, 0.f};

  bf16x8 a[4], b[4];

  // prologue
  STAGE(0, 0);
  __syncthreads();

  for (int kt = 0; kt < NT; ++kt) {
    const int p = kt & 1;
    if (kt + 1 < NT) STAGE(p ^ 1, kt + 1);
    const char* ab = smem + p * 24576 + (wr * 4) * 1024 + lt;          // A subtile wr*4+m
    const char* bb = smem + p * 24576 + 16384 + (wc * 4) * 1024 + lt;  // B subtile wc*4+n
#pragma unroll
    for (int m = 0; m < 4; ++m) a[m] = *(const bf16x8*)(ab + m * 1024);
#pragma unroll
    for (int n = 0; n < 4; ++n) b[n] = *(const bf16x8*)(bb + n * 1024);
#pragma unroll
    for (int m = 0; m < 4; ++m)
#pragma unroll
      for (int n = 0; n < 4; ++n)
        acc[m][n] = MF(a[m], b[n], acc[m][n]);
    __syncthreads();
  }

  // epilogue: wave piece rows wr*64+m*16, cols wc*64+n*16
#pragma unroll
  for (int m = 0; m < 4; ++m) {
    const int rbase = wr * 64 + m * 16 + (lane >> 4) * 4;
#pragma unroll
    for (int n = 0; n < 4; ++n) {
      const int col = n0 + wc * 64 + n * 16 + (lane & 15);
      const float bv_ = bias[(size_t)e * NTOT + col];
#pragma unroll
      for (int j = 0; j < 4; ++j) {
        const int r = rbase + j;
        if (r < vrows) {
          float vv = acc[m][n][j] + bv_;
          if constexpr (GELU) vv = 0.5f * vv * (1.0f + erff(vv * 0.70710678f));
          Outm[(size_t)(row0 + r) * NTOT + col] = f2bf(vv);
        }
      }
    }
  }
}

// -------------------- combine: out[t] = g0*Y[p0] + g1*Y[p1] --------------------
__global__ __launch_bounds__(256) void k_combine(
    const unsigned short* __restrict__ Y, const int* __restrict__ tok_pos,
    const float* __restrict__ gates, float* __restrict__ out) {
  int t = blockIdx.x, tid = threadIdx.x;
  int p0 = tok_pos[2 * t], p1 = tok_pos[2 * t + 1];
  float g0 = gates[2 * t], g1 = gates[2 * t + 1];
  ushort4 y0 = ((const ushort4*)(Y + (size_t)p0 * DD))[tid];
  ushort4 y1 = ((const ushort4*)(Y + (size_t)p1 * DD))[tid];
  float4 o;
  o.x = g0 * bf2f(y0.x) + g1 * bf2f(y1.x);
  o.y = g0 * bf2f(y0.y) + g1 * bf2f(y1.y);
  o.z = g0 * bf2f(y0.z) + g1 * bf2f(y1.z);
  o.w = g0 * bf2f(y0.w) + g1 * bf2f(y1.w);
  ((float4*)(out + (size_t)t * DD))[tid] = o;
}

__global__ __launch_bounds__(256) void k_sentinel(float* out, int n) {
  int i = blockIdx.x * 256 + threadIdx.x;
  if (i < n) out[i] = 12345.0f;
}

extern "C" void kernel_launch(void* const* d_in, const int* in_sizes, int n_in,
                              void* d_out, int out_size, void* d_ws, size_t ws_size,
                              hipStream_t stream) {
  const float* x   = (const float*)d_in[0];
  const float* rls = (const float*)d_in[1];
  const float* rlb = (const float*)d_in[2];
  const float* rw  = (const float*)d_in[3];
  const float* rb  = (const float*)d_in[4];
  const float* els = (const float*)d_in[5];
  const float* elb = (const float*)d_in[6];
  const float* w1  = (const float*)d_in[7];
  const float* b1  = (const float*)d_in[8];
  const float* w2  = (const float*)d_in[9];
  const float* b2  = (const float*)d_in[10];
  float* out = (float*)d_out;

  char* wsb = (char*)d_ws;
  size_t o = 0;
  int* ctrl = (int*)(wsb + o);                    o += 256;
  int* tok_pos = (int*)(wsb + o);                 o += (size_t)SLOTS * 4;
  float* gates = (float*)(wsb + o);               o += (size_t)SLOTS * 4;
  int* topk = (int*)(wsb + o);                    o += (size_t)TT * 4;
  int* ranks = (int*)(wsb + o);                   o += (size_t)SLOTS * 4;
  int* blkcnt = (int*)(wsb + o);                  o += (size_t)NRB * EE * 4;
  unsigned short* xhat = (unsigned short*)(wsb + o); o += (size_t)TT * DD * 2;
  unsigned short* Abuf = (unsigned short*)(wsb + o); o += (size_t)SLOTSP * DD * 2;
  unsigned short* w1b = (unsigned short*)(wsb + o);  o += (size_t)EE * HH * DD * 2;
  unsigned short* w2b = (unsigned short*)(wsb + o);  o += (size_t)EE * DD * HH * 2;
  unsigned short* Hm = (unsigned short*)(wsb + o);   o += (size_t)SLOTSP * HH * 2;
  unsigned short* Yb = (unsigned short*)(wsb + o);   o += (size_t)SLOTSP * DD * 2;

  if (ws_size < o) {
    k_sentinel<<<(out_size + 255) / 256, 256, 0, stream>>>(out, out_size);
    return;
  }

  k_fused_rw<<<NRB + NWB, 256, 0, stream>>>(x, rls, rlb, rw, rb, w1, w2, xhat,
                                            topk, gates, ranks, blkcnt, w1b, w2b);
  k_offsets<<<1, 256, 0, stream>>>(ctrl, blkcnt);
  k_build<<<SLOTS / 2, 256, 0, stream>>>(xhat, els, elb, ctrl, topk, ranks,
                                         blkcnt, Abuf, tok_pos);
  k_gemm6<DD, true><<<dim3(MAXRT2, HH / 128), 512, 0, stream>>>(Abuf, w1b, b1, Hm, ctrl, HH);
  k_gemm6<HH, false><<<dim3(MAXRT2, DD / 128), 512, 0, stream>>>(Hm, w2b, b2, Yb, ctrl, DD);
  k_combine<<<TT, 256, 0, stream>>>(Yb, tok_pos, gates, out);
}

// Round 15
// 583.787 us; speedup vs baseline: 2.9559x; 2.9559x over previous
//
#include <hip/hip_runtime.h>
#include <hip/hip_bf16.h>

#define TT 8192      // tokens
#define DD 1024
#define EE 8
#define HH 4096
#define SLOTS 16384  // TT * K
#define SLOTSP (SLOTS + 256)
#define MAXRT2 (SLOTS / 256 + EE)  // 72 worst-case 256-row tiles
#define NRB 2048                   // router blocks (4 tokens each)
#define NWB 2048                   // wconv blocks (grid-stride)

typedef __bf16 bf16x8 __attribute__((ext_vector_type(8)));
typedef float f32x4 __attribute__((ext_vector_type(4)));

__device__ __forceinline__ float bf2f(unsigned u) { return __uint_as_float(u << 16); }
__device__ __forceinline__ unsigned short f2bf(float f) {
  __hip_bfloat16 h = __float2bfloat16(f);
  return __builtin_bit_cast(unsigned short, h);
}
__device__ __forceinline__ f32x4 MF(bf16x8 a, bf16x8 b, f32x4 c) {
  return __builtin_amdgcn_mfma_f32_16x16x32_bf16(a, b, c, 0, 0, 0);
}

// ctrl layout (ints): [0..7]=cnt  [8..16]=off  [25..33]=rtp (256-row tiles)

// ============ fused: router (blocks 0..NRB-1, 4 tok/blk, NO atomics) ============
// ============         + weight fp32->bf16 (blocks NRB..NRB+NWB-1)    ============
__global__ __launch_bounds__(256) void k_fused_rw(
    const float* __restrict__ x, const float* __restrict__ rls,
    const float* __restrict__ rlb, const float* __restrict__ rw,
    const float* __restrict__ rb, const float* __restrict__ w1,
    const float* __restrict__ w2, unsigned short* __restrict__ xhat,
    int* __restrict__ topk, float* __restrict__ gates, int* __restrict__ ranks,
    int* __restrict__ blkcnt, unsigned short* __restrict__ w1b,
    unsigned short* __restrict__ w2b) {
  if (blockIdx.x >= NRB) {
    const size_t n4t = (size_t)2 * EE * HH * DD / 4;
    const size_t n4w1 = (size_t)EE * HH * DD / 4;
    size_t i = (size_t)(blockIdx.x - NRB) * 256 + threadIdx.x;
    const size_t stride = (size_t)NWB * 256;
    for (; i < n4t; i += stride) {
      const float4* src; unsigned short* dst; size_t j;
      if (i < n4w1) { src = (const float4*)w1; dst = w1b; j = i; }
      else          { src = (const float4*)w2; dst = w2b; j = i - n4w1; }
      float4 v = src[j];
      ushort4 ov;
      ov.x = f2bf(v.x); ov.y = f2bf(v.y); ov.z = f2bf(v.z); ov.w = f2bf(v.w);
      ((ushort4*)dst)[j] = ov;
    }
    return;
  }
  const int tid = threadIdx.x, lane = tid & 63, v = tid >> 6;
  const int t = blockIdx.x * 4 + v;
  __shared__ int sh_e[4][2];
  const float4* xr = (const float4*)(x + (size_t)t * DD);
  float4 xv[4];
#pragma unroll
  for (int j = 0; j < 4; ++j) xv[j] = xr[lane + 64 * j];
  float s = 0.f, s2 = 0.f;
#pragma unroll
  for (int j = 0; j < 4; ++j) {
    s += xv[j].x + xv[j].y + xv[j].z + xv[j].w;
    s2 += xv[j].x * xv[j].x + xv[j].y * xv[j].y + xv[j].z * xv[j].z + xv[j].w * xv[j].w;
  }
#pragma unroll
  for (int o = 32; o > 0; o >>= 1) { s += __shfl_xor(s, o); s2 += __shfl_xor(s2, o); }
  const float mean = s * (1.0f / DD);
  const float var = s2 * (1.0f / DD) - mean * mean;
  const float inv = rsqrtf(var + 1e-6f);
  float xh[4][4];
  unsigned short* xo = xhat + (size_t)t * DD;
#pragma unroll
  for (int j = 0; j < 4; ++j) {
    xh[j][0] = (xv[j].x - mean) * inv; xh[j][1] = (xv[j].y - mean) * inv;
    xh[j][2] = (xv[j].z - mean) * inv; xh[j][3] = (xv[j].w - mean) * inv;
    ushort4 pk;
    pk.x = f2bf(xh[j][0]); pk.y = f2bf(xh[j][1]);
    pk.z = f2bf(xh[j][2]); pk.w = f2bf(xh[j][3]);
    ((ushort4*)xo)[lane + 64 * j] = pk;
  }
  float r[4][4];
#pragma unroll
  for (int j = 0; j < 4; ++j) {
    float4 sc = ((const float4*)rls)[lane + 64 * j];
    float4 bi = ((const float4*)rlb)[lane + 64 * j];
    r[j][0] = fmaf(xh[j][0], sc.x, bi.x); r[j][1] = fmaf(xh[j][1], sc.y, bi.y);
    r[j][2] = fmaf(xh[j][2], sc.z, bi.z); r[j][3] = fmaf(xh[j][3], sc.w, bi.w);
  }
  float pe[EE];
#pragma unroll
  for (int e = 0; e < EE; ++e) {
    float acc = 0.f;
#pragma unroll
    for (int j = 0; j < 4; ++j) {
      float4 w = ((const float4*)(rw + (size_t)e * DD))[lane + 64 * j];
      acc = fmaf(r[j][0], w.x, fmaf(r[j][1], w.y, fmaf(r[j][2], w.z, fmaf(r[j][3], w.w, acc))));
    }
    pe[e] = acc;
  }
#pragma unroll
  for (int o = 32; o > 0; o >>= 1) {
#pragma unroll
    for (int e = 0; e < EE; ++e) pe[e] += __shfl_xor(pe[e], o);
  }
  int i1 = 0, i2 = -1;
  if (lane == 0) {
    float lg[EE];
    for (int e = 0; e < EE; ++e) lg[e] = pe[e] + rb[e];
    for (int e = 1; e < EE; ++e) if (lg[e] > lg[i1]) i1 = e;
    for (int e = 0; e < EE; ++e) { if (e == i1) continue; if (i2 < 0 || lg[e] > lg[i2]) i2 = e; }
    float eb = expf(lg[i2] - lg[i1]);
    float den = 1.0f / (1.0f + eb);
    topk[t] = i1 | (i2 << 8);
    gates[2 * t] = den;
    gates[2 * t + 1] = eb * den;
    sh_e[v][0] = i1; sh_e[v][1] = i2;
  }
  __syncthreads();
  if (lane == 0) {
    int r0 = 0, r1 = 0;
    for (int q = 0; q < 2 * v; ++q) {
      int ee = sh_e[q >> 1][q & 1];
      r0 += (ee == i1); r1 += (ee == i2);
    }
    ranks[2 * t] = r0;
    ranks[2 * t + 1] = r1;
  }
  if (tid < EE) {
    int c = 0;
    for (int q = 0; q < 8; ++q) c += (sh_e[q >> 1][q & 1] == tid);
    blkcnt[blockIdx.x * EE + tid] = c;
  }
}

// ---- offsets: two-level scan over blkcnt[NRB][8] -> per-block bases + ctrl ----
__global__ __launch_bounds__(256) void k_offsets(int* __restrict__ ctrl,
                                                 int* __restrict__ blkcnt) {
  __shared__ int chunk[32 * EE];
  __shared__ int tot[EE];
  const int t = threadIdx.x, e = t & 7, c = t >> 3;
  int s = 0;
  for (int i = 0; i < 64; ++i) s += blkcnt[(c * 64 + i) * EE + e];
  chunk[c * EE + e] = s;
  __syncthreads();
  if (t < EE) {
    int run = 0;
    for (int c2 = 0; c2 < 32; ++c2) { int vv = chunk[c2 * EE + t]; chunk[c2 * EE + t] = run; run += vv; }
    tot[t] = run;
    ctrl[t] = run;
  }
  __syncthreads();
  if (t == 0) {
    int o = 0, rr = 0;
    ctrl[8] = 0; ctrl[25] = 0;
    for (int e2 = 0; e2 < EE; ++e2) {
      int cc = tot[e2];
      o += cc; ctrl[9 + e2] = o;
      rr += (cc + 255) >> 8; ctrl[26 + e2] = rr;   // 256-row tiles
    }
  }
  int run = chunk[c * EE + e];
  for (int i = 0; i < 64; ++i) {
    int idx = (c * 64 + i) * EE + e;
    int vv = blkcnt[idx];
    blkcnt[idx] = run;
    run += vv;
  }
}

// ---- build A rows (expert LN applied to xhat); pos from scan, no atomics ----
__global__ __launch_bounds__(256) void k_build(
    const unsigned short* __restrict__ xhat, const float* __restrict__ els,
    const float* __restrict__ elb, const int* __restrict__ ctrl,
    const int* __restrict__ topk, const int* __restrict__ ranks,
    const int* __restrict__ blkbase, unsigned short* __restrict__ A,
    int* __restrict__ tok_pos) {
  int p = blockIdx.x * 2 + (threadIdx.x >> 7);
  int t = p >> 1, k = p & 1, tid = threadIdx.x & 127;
  int e = (topk[t] >> (k * 8)) & 0xff;
  int pos = ctrl[8 + e] + blkbase[(p >> 3) * EE + e] + ranks[p];
  if (tid == 0) tok_pos[p] = pos;
  int i = tid * 8;
  uint4 xv = *(const uint4*)(xhat + (size_t)t * DD + i);
  const float* sp = els + (size_t)e * DD + i;
  const float* bp = elb + (size_t)e * DD + i;
  float4 s0 = *(const float4*)sp, s1 = *(const float4*)(sp + 4);
  float4 b0 = *(const float4*)bp, b1 = *(const float4*)(bp + 4);
  unsigned r0 = (unsigned)f2bf(fmaf(bf2f(xv.x & 0xffffu), s0.x, b0.x)) |
                ((unsigned)f2bf(fmaf(bf2f(xv.x >> 16), s0.y, b0.y)) << 16);
  unsigned r1 = (unsigned)f2bf(fmaf(bf2f(xv.y & 0xffffu), s0.z, b0.z)) |
                ((unsigned)f2bf(fmaf(bf2f(xv.y >> 16), s0.w, b0.w)) << 16);
  unsigned r2 = (unsigned)f2bf(fmaf(bf2f(xv.z & 0xffffu), s1.x, b1.x)) |
                ((unsigned)f2bf(fmaf(bf2f(xv.z >> 16), s1.y, b1.y)) << 16);
  unsigned r3 = (unsigned)f2bf(fmaf(bf2f(xv.w & 0xffffu), s1.z, b1.z)) |
                ((unsigned)f2bf(fmaf(bf2f(xv.w >> 16), s1.w, b1.w)) << 16);
  uint4 ov; ov.x = r0; ov.y = r1; ov.z = r2; ov.w = r3;
  *(uint4*)(A + (size_t)pos * DD + i) = ov;
}

// == grouped GEMM, BM=256 x BN=128, BK=32, 512thr/8 waves (R15: spill fixed) ==
// R14's (512,6) capped VGPR at ~85 < the ~115 this wave needs -> acc spilled
// to scratch (WRITE_SIZE 1.7GB, MfmaUtil 6%). R15: __launch_bounds__(512,4)
// -> 128 VGPR cap, no spill; occupancy 2 blocks/CU (16 waves/CU vs R11's 12).
// Per-wave output 64x64 (acc[4][4]) — same per-wave mix as R11.
// LDS: buf p at p*24576: A 256x32 (16KB) + B 128x32 (8KB); st_16x32 swizzle.
// Loop = R8 unpinned 2-phase. Block order = XCD swizzle + A-panel-major.
#define GLL(S, D)                                                              \
  __builtin_amdgcn_global_load_lds(                                            \
      (const __attribute__((address_space(1))) unsigned int*)(S),              \
      (__attribute__((address_space(3))) unsigned int*)(D), 16, 0, 0)
// wave w stages A subtiles {2w,2w+1} (rows 32w+ri, 32w+16+ri) + B subtile {w}
#define STAGE(P, KT) do {                                                      \
    const unsigned short* sA_ = pA + (size_t)(KT) * 32;                        \
    const unsigned short* sB_ = pB + (size_t)(KT) * 32;                        \
    char* dA_ = sLA + (P) * 24576;                                             \
    char* dB_ = sLB + (P) * 24576;                                             \
    GLL(sA_, dA_); GLL(sA_ + 16 * KDIM, dA_ + 1024);                           \
    GLL(sB_, dB_);                                                             \
  } while (0)

template <int KDIM, bool GELU>
__global__ __launch_bounds__(512, 4) void k_gemm6(
    const unsigned short* __restrict__ Amat,  // [SLOTSP][KDIM] bf16
    const unsigned short* __restrict__ W,     // [EE][NTOT][KDIM] bf16
    const float* __restrict__ bias,           // [EE][NTOT]
    unsigned short* __restrict__ Outm,        // [SLOTSP][NTOT] bf16
    const int* __restrict__ ctrl, int NTOT) {
  constexpr int NT = KDIM / 32;
  __shared__ __align__(16) char smem[49152];
  const int* rtp = ctrl + 25;

  // bijective XCD swizzle (m204) + A-panel-major order (R11 config)
  const int nwg = gridDim.x * gridDim.y;
  const int lin = blockIdx.y * gridDim.x + blockIdx.x;
  const int xcd = lin & 7, loc = lin >> 3;
  const int q = nwg >> 3, rr = nwg & 7;
  const int lin2 = (xcd < rr ? xcd * (q + 1) : rr * (q + 1) + (xcd - rr) * q) + loc;
  const int by = lin2 % gridDim.y;
  const int bx = lin2 / gridDim.y;
  if (bx >= rtp[EE]) return;
  int e = 0;
  while (bx >= rtp[e + 1]) ++e;
  const int rt = bx - rtp[e];
  const int row0 = ctrl[8 + e] + rt * 256;
  int vrows = ctrl[e] - rt * 256;
  if (vrows > 256) vrows = 256;
  const int n0 = by * 128;

  const int tid = threadIdx.x, lane = tid & 63, w = tid >> 6;
  const int wr = w >> 1, wc = w & 1;  // 4M x 2N waves; per-wave out 64x64

  // staging lane geometry (inverse swizzle on the global source)
  const int u = (lane * 16) ^ (((lane >> 5) & 1) << 5);
  const int ri = u >> 6;         // in-subtile row 0..15
  const int ci = (u & 63) >> 1;  // in-subtile col elem 0/8/16/24
  const unsigned short* pA = Amat + (size_t)(row0 + 32 * w + ri) * KDIM + ci;
  const unsigned short* pB = W + ((size_t)e * NTOT + n0 + 16 * w + ri) * KDIM + ci;
  char* sLA = smem + (2 * w) * 1024 + lane * 16;          // A subtiles 2w,2w+1
  char* sLB = smem + 16384 + w * 1024 + lane * 16;        // B subtile w

  // fragment-read lane term (swizzled): row=lane&15, col byte=(lane>>4)*16
  const int lt = (((lane & 15) << 6) | ((lane >> 4) << 4)) ^ (((lane >> 3) & 1) << 5);

  f32x4 acc[4][4];
#pragma unroll
  for (int m = 0; m < 4; ++m)
#pragma unroll
    for (int n = 0; n < 4; ++n) acc[m][n] = (f32x4){0.f, 0.f, 0.f, 0.f};

  bf16x8 a[4], b[4];

  // prologue
  STAGE(0, 0);
  __syncthreads();

  for (int kt = 0; kt < NT; ++kt) {
    const int p = kt & 1;
    if (kt + 1 < NT) STAGE(p ^ 1, kt + 1);
    const char* ab = smem + p * 24576 + (wr * 4) * 1024 + lt;          // A subtile wr*4+m
    const char* bb = smem + p * 24576 + 16384 + (wc * 4) * 1024 + lt;  // B subtile wc*4+n
#pragma unroll
    for (int m = 0; m < 4; ++m) a[m] = *(const bf16x8*)(ab + m * 1024);
#pragma unroll
    for (int n = 0; n < 4; ++n) b[n] = *(const bf16x8*)(bb + n * 1024);
#pragma unroll
    for (int m = 0; m < 4; ++m)
#pragma unroll
      for (int n = 0; n < 4; ++n)
        acc[m][n] = MF(a[m], b[n], acc[m][n]);
    __syncthreads();
  }

  // epilogue: wave piece rows wr*64+m*16, cols wc*64+n*16
#pragma unroll
  for (int m = 0; m < 4; ++m) {
    const int rbase = wr * 64 + m * 16 + (lane >> 4) * 4;
#pragma unroll
    for (int n = 0; n < 4; ++n) {
      const int col = n0 + wc * 64 + n * 16 + (lane & 15);
      const float bv_ = bias[(size_t)e * NTOT + col];
#pragma unroll
      for (int j = 0; j < 4; ++j) {
        const int r = rbase + j;
        if (r < vrows) {
          float vv = acc[m][n][j] + bv_;
          if constexpr (GELU) vv = 0.5f * vv * (1.0f + erff(vv * 0.70710678f));
          Outm[(size_t)(row0 + r) * NTOT + col] = f2bf(vv);
        }
      }
    }
  }
}

// -------------------- combine: out[t] = g0*Y[p0] + g1*Y[p1] --------------------
__global__ __launch_bounds__(256) void k_combine(
    const unsigned short* __restrict__ Y, const int* __restrict__ tok_pos,
    const float* __restrict__ gates, float* __restrict__ out) {
  int t = blockIdx.x, tid = threadIdx.x;
  int p0 = tok_pos[2 * t], p1 = tok_pos[2 * t + 1];
  float g0 = gates[2 * t], g1 = gates[2 * t + 1];
  ushort4 y0 = ((const ushort4*)(Y + (size_t)p0 * DD))[tid];
  ushort4 y1 = ((const ushort4*)(Y + (size_t)p1 * DD))[tid];
  float4 o;
  o.x = g0 * bf2f(y0.x) + g1 * bf2f(y1.x);
  o.y = g0 * bf2f(y0.y) + g1 * bf2f(y1.y);
  o.z = g0 * bf2f(y0.z) + g1 * bf2f(y1.z);
  o.w = g0 * bf2f(y0.w) + g1 * bf2f(y1.w);
  ((float4*)(out + (size_t)t * DD))[tid] = o;
}

__global__ __launch_bounds__(256) void k_sentinel(float* out, int n) {
  int i = blockIdx.x * 256 + threadIdx.x;
  if (i < n) out[i] = 12345.0f;
}

extern "C" void kernel_launch(void* const* d_in, const int* in_sizes, int n_in,
                              void* d_out, int out_size, void* d_ws, size_t ws_size,
                              hipStream_t stream) {
  const float* x   = (const float*)d_in[0];
  const float* rls = (const float*)d_in[1];
  const float* rlb = (const float*)d_in[2];
  const float* rw  = (const float*)d_in[3];
  const float* rb  = (const float*)d_in[4];
  const float* els = (const float*)d_in[5];
  const float* elb = (const float*)d_in[6];
  const float* w1  = (const float*)d_in[7];
  const float* b1  = (const float*)d_in[8];
  const float* w2  = (const float*)d_in[9];
  const float* b2  = (const float*)d_in[10];
  float* out = (float*)d_out;

  char* wsb = (char*)d_ws;
  size_t o = 0;
  int* ctrl = (int*)(wsb + o);                    o += 256;
  int* tok_pos = (int*)(wsb + o);                 o += (size_t)SLOTS * 4;
  float* gates = (float*)(wsb + o);               o += (size_t)SLOTS * 4;
  int* topk = (int*)(wsb + o);                    o += (size_t)TT * 4;
  int* ranks = (int*)(wsb + o);                   o += (size_t)SLOTS * 4;
  int* blkcnt = (int*)(wsb + o);                  o += (size_t)NRB * EE * 4;
  unsigned short* xhat = (unsigned short*)(wsb + o); o += (size_t)TT * DD * 2;
  unsigned short* Abuf = (unsigned short*)(wsb + o); o += (size_t)SLOTSP * DD * 2;
  unsigned short* w1b = (unsigned short*)(wsb + o);  o += (size_t)EE * HH * DD * 2;
  unsigned short* w2b = (unsigned short*)(wsb + o);  o += (size_t)EE * DD * HH * 2;
  unsigned short* Hm = (unsigned short*)(wsb + o);   o += (size_t)SLOTSP * HH * 2;
  unsigned short* Yb = (unsigned short*)(wsb + o);   o += (size_t)SLOTSP * DD * 2;

  if (ws_size < o) {
    k_sentinel<<<(out_size + 255) / 256, 256, 0, stream>>>(out, out_size);
    return;
  }

  k_fused_rw<<<NRB + NWB, 256, 0, stream>>>(x, rls, rlb, rw, rb, w1, w2, xhat,
                                            topk, gates, ranks, blkcnt, w1b, w2b);
  k_offsets<<<1, 256, 0, stream>>>(ctrl, blkcnt);
  k_build<<<SLOTS / 2, 256, 0, stream>>>(xhat, els, elb, ctrl, topk, ranks,
                                         blkcnt, Abuf, tok_pos);
  k_gemm6<DD, true><<<dim3(MAXRT2, HH / 128), 512, 0, stream>>>(Abuf, w1b, b1, Hm, ctrl, HH);
  k_gemm6<HH, false><<<dim3(MAXRT2, DD / 128), 512, 0, stream>>>(Hm, w2b, b2, Yb, ctrl, DD);
  k_combine<<<TT, 256, 0, stream>>>(Yb, tok_pos, gates, out);
}

// Round 16
// 570.585 us; speedup vs baseline: 3.0243x; 1.0231x over previous
//
#include <hip/hip_runtime.h>
#include <hip/hip_bf16.h>

#define TT 8192      // tokens
#define DD 1024
#define EE 8
#define HH 4096
#define SLOTS 16384  // TT * K
#define SLOTSP (SLOTS + 256)
#define MAXRT1 (SLOTS / 128 + EE)  // 136 worst-case 128-row tiles
#define NRB 2048                   // router blocks (4 tokens each)
#define NWB 2048                   // wconv blocks (grid-stride)

typedef __bf16 bf16x8 __attribute__((ext_vector_type(8)));
typedef float f32x4 __attribute__((ext_vector_type(4)));

__device__ __forceinline__ float bf2f(unsigned u) { return __uint_as_float(u << 16); }
__device__ __forceinline__ unsigned short f2bf(float f) {
  __hip_bfloat16 h = __float2bfloat16(f);
  return __builtin_bit_cast(unsigned short, h);
}
__device__ __forceinline__ f32x4 MF(bf16x8 a, bf16x8 b, f32x4 c) {
  return __builtin_amdgcn_mfma_f32_16x16x32_bf16(a, b, c, 0, 0, 0);
}

// ctrl layout (ints): [0..7]=cnt  [8..16]=off  [25..33]=rtp (128-row tiles)

// ============ fused: router (blocks 0..NRB-1, 4 tok/blk, NO atomics) ============
// ============         + weight fp32->bf16 (blocks NRB..NRB+NWB-1)    ============
__global__ __launch_bounds__(256) void k_fused_rw(
    const float* __restrict__ x, const float* __restrict__ rls,
    const float* __restrict__ rlb, const float* __restrict__ rw,
    const float* __restrict__ rb, const float* __restrict__ w1,
    const float* __restrict__ w2, unsigned short* __restrict__ xhat,
    int* __restrict__ topk, float* __restrict__ gates, int* __restrict__ ranks,
    int* __restrict__ blkcnt, unsigned short* __restrict__ w1b,
    unsigned short* __restrict__ w2b) {
  if (blockIdx.x >= NRB) {
    const size_t n4t = (size_t)2 * EE * HH * DD / 4;
    const size_t n4w1 = (size_t)EE * HH * DD / 4;
    size_t i = (size_t)(blockIdx.x - NRB) * 256 + threadIdx.x;
    const size_t stride = (size_t)NWB * 256;
    for (; i < n4t; i += stride) {
      const float4* src; unsigned short* dst; size_t j;
      if (i < n4w1) { src = (const float4*)w1; dst = w1b; j = i; }
      else          { src = (const float4*)w2; dst = w2b; j = i - n4w1; }
      float4 v = src[j];
      ushort4 ov;
      ov.x = f2bf(v.x); ov.y = f2bf(v.y); ov.z = f2bf(v.z); ov.w = f2bf(v.w);
      ((ushort4*)dst)[j] = ov;
    }
    return;
  }
  const int tid = threadIdx.x, lane = tid & 63, v = tid >> 6;
  const int t = blockIdx.x * 4 + v;
  __shared__ int sh_e[4][2];
  const float4* xr = (const float4*)(x + (size_t)t * DD);
  float4 xv[4];
#pragma unroll
  for (int j = 0; j < 4; ++j) xv[j] = xr[lane + 64 * j];
  float s = 0.f, s2 = 0.f;
#pragma unroll
  for (int j = 0; j < 4; ++j) {
    s += xv[j].x + xv[j].y + xv[j].z + xv[j].w;
    s2 += xv[j].x * xv[j].x + xv[j].y * xv[j].y + xv[j].z * xv[j].z + xv[j].w * xv[j].w;
  }
#pragma unroll
  for (int o = 32; o > 0; o >>= 1) { s += __shfl_xor(s, o); s2 += __shfl_xor(s2, o); }
  const float mean = s * (1.0f / DD);
  const float var = s2 * (1.0f / DD) - mean * mean;
  const float inv = rsqrtf(var + 1e-6f);
  float xh[4][4];
  unsigned short* xo = xhat + (size_t)t * DD;
#pragma unroll
  for (int j = 0; j < 4; ++j) {
    xh[j][0] = (xv[j].x - mean) * inv; xh[j][1] = (xv[j].y - mean) * inv;
    xh[j][2] = (xv[j].z - mean) * inv; xh[j][3] = (xv[j].w - mean) * inv;
    ushort4 pk;
    pk.x = f2bf(xh[j][0]); pk.y = f2bf(xh[j][1]);
    pk.z = f2bf(xh[j][2]); pk.w = f2bf(xh[j][3]);
    ((ushort4*)xo)[lane + 64 * j] = pk;
  }
  float r[4][4];
#pragma unroll
  for (int j = 0; j < 4; ++j) {
    float4 sc = ((const float4*)rls)[lane + 64 * j];
    float4 bi = ((const float4*)rlb)[lane + 64 * j];
    r[j][0] = fmaf(xh[j][0], sc.x, bi.x); r[j][1] = fmaf(xh[j][1], sc.y, bi.y);
    r[j][2] = fmaf(xh[j][2], sc.z, bi.z); r[j][3] = fmaf(xh[j][3], sc.w, bi.w);
  }
  float pe[EE];
#pragma unroll
  for (int e = 0; e < EE; ++e) {
    float acc = 0.f;
#pragma unroll
    for (int j = 0; j < 4; ++j) {
      float4 w = ((const float4*)(rw + (size_t)e * DD))[lane + 64 * j];
      acc = fmaf(r[j][0], w.x, fmaf(r[j][1], w.y, fmaf(r[j][2], w.z, fmaf(r[j][3], w.w, acc))));
    }
    pe[e] = acc;
  }
#pragma unroll
  for (int o = 32; o > 0; o >>= 1) {
#pragma unroll
    for (int e = 0; e < EE; ++e) pe[e] += __shfl_xor(pe[e], o);
  }
  int i1 = 0, i2 = -1;
  if (lane == 0) {
    float lg[EE];
    for (int e = 0; e < EE; ++e) lg[e] = pe[e] + rb[e];
    for (int e = 1; e < EE; ++e) if (lg[e] > lg[i1]) i1 = e;
    for (int e = 0; e < EE; ++e) { if (e == i1) continue; if (i2 < 0 || lg[e] > lg[i2]) i2 = e; }
    float eb = expf(lg[i2] - lg[i1]);
    float den = 1.0f / (1.0f + eb);
    topk[t] = i1 | (i2 << 8);
    gates[2 * t] = den;
    gates[2 * t + 1] = eb * den;
    sh_e[v][0] = i1; sh_e[v][1] = i2;
  }
  __syncthreads();
  if (lane == 0) {
    int r0 = 0, r1 = 0;
    for (int q = 0; q < 2 * v; ++q) {
      int ee = sh_e[q >> 1][q & 1];
      r0 += (ee == i1); r1 += (ee == i2);
    }
    ranks[2 * t] = r0;
    ranks[2 * t + 1] = r1;
  }
  if (tid < EE) {
    int c = 0;
    for (int q = 0; q < 8; ++q) c += (sh_e[q >> 1][q & 1] == tid);
    blkcnt[blockIdx.x * EE + tid] = c;
  }
}

// ---- offsets: two-level scan over blkcnt[NRB][8] -> per-block bases + ctrl ----
__global__ __launch_bounds__(256) void k_offsets(int* __restrict__ ctrl,
                                                 int* __restrict__ blkcnt) {
  __shared__ int chunk[32 * EE];
  __shared__ int tot[EE];
  const int t = threadIdx.x, e = t & 7, c = t >> 3;
  int s = 0;
  for (int i = 0; i < 64; ++i) s += blkcnt[(c * 64 + i) * EE + e];
  chunk[c * EE + e] = s;
  __syncthreads();
  if (t < EE) {
    int run = 0;
    for (int c2 = 0; c2 < 32; ++c2) { int vv = chunk[c2 * EE + t]; chunk[c2 * EE + t] = run; run += vv; }
    tot[t] = run;
    ctrl[t] = run;
  }
  __syncthreads();
  if (t == 0) {
    int o = 0, rr = 0;
    ctrl[8] = 0; ctrl[25] = 0;
    for (int e2 = 0; e2 < EE; ++e2) {
      int cc = tot[e2];
      o += cc; ctrl[9 + e2] = o;
      rr += (cc + 127) >> 7; ctrl[26 + e2] = rr;   // 128-row tiles
    }
  }
  int run = chunk[c * EE + e];
  for (int i = 0; i < 64; ++i) {
    int idx = (c * 64 + i) * EE + e;
    int vv = blkcnt[idx];
    blkcnt[idx] = run;  // becomes per-block base
    run += vv;
  }
}

// ---- build A rows (expert LN applied to xhat); pos from scan, no atomics ----
__global__ __launch_bounds__(256) void k_build(
    const unsigned short* __restrict__ xhat, const float* __restrict__ els,
    const float* __restrict__ elb, const int* __restrict__ ctrl,
    const int* __restrict__ topk, const int* __restrict__ ranks,
    const int* __restrict__ blkbase, unsigned short* __restrict__ A,
    int* __restrict__ tok_pos) {
  int p = blockIdx.x * 2 + (threadIdx.x >> 7);
  int t = p >> 1, k = p & 1, tid = threadIdx.x & 127;
  int e = (topk[t] >> (k * 8)) & 0xff;
  int pos = ctrl[8 + e] + blkbase[(p >> 3) * EE + e] + ranks[p];
  if (tid == 0) tok_pos[p] = pos;
  int i = tid * 8;
  uint4 xv = *(const uint4*)(xhat + (size_t)t * DD + i);
  const float* sp = els + (size_t)e * DD + i;
  const float* bp = elb + (size_t)e * DD + i;
  float4 s0 = *(const float4*)sp, s1 = *(const float4*)(sp + 4);
  float4 b0 = *(const float4*)bp, b1 = *(const float4*)(bp + 4);
  unsigned r0 = (unsigned)f2bf(fmaf(bf2f(xv.x & 0xffffu), s0.x, b0.x)) |
                ((unsigned)f2bf(fmaf(bf2f(xv.x >> 16), s0.y, b0.y)) << 16);
  unsigned r1 = (unsigned)f2bf(fmaf(bf2f(xv.y & 0xffffu), s0.z, b0.z)) |
                ((unsigned)f2bf(fmaf(bf2f(xv.y >> 16), s0.w, b0.w)) << 16);
  unsigned r2 = (unsigned)f2bf(fmaf(bf2f(xv.z & 0xffffu), s1.x, b1.x)) |
                ((unsigned)f2bf(fmaf(bf2f(xv.z >> 16), s1.y, b1.y)) << 16);
  unsigned r3 = (unsigned)f2bf(fmaf(bf2f(xv.w & 0xffffu), s1.z, b1.z)) |
                ((unsigned)f2bf(fmaf(bf2f(xv.w >> 16), s1.w, b1.w)) << 16);
  uint4 ov; ov.x = r0; ov.y = r1; ov.z = r2; ov.w = r3;
  *(uint4*)(A + (size_t)pos * DD + i) = ov;
}

// ==== grouped GEMM, 128x128, BK=32, ~3 blocks/CU (R11 best-measured form) ====
// STAGE(p^1) -> 8 ds_read -> 16 MFMA -> __syncthreads(); st_16x32 swizzle
// both-sides; A-panel-major + bijective XCD block order. 245 us/GEMM measured.
#define GLL(S, D)                                                              \
  __builtin_amdgcn_global_load_lds(                                            \
      (const __attribute__((address_space(1))) unsigned int*)(S),              \
      (__attribute__((address_space(3))) unsigned int*)(D), 16, 0, 0)
#define STAGE(P, KT) do {                                                      \
    const unsigned short* sA_ = pA + (size_t)(KT) * 32;                        \
    const unsigned short* sB_ = pB + (size_t)(KT) * 32;                        \
    char* dA_ = sL + (P) * 16384;                                              \
    char* dB_ = dA_ + 8192;                                                    \
    GLL(sA_, dA_); GLL(sA_ + 16 * KDIM, dA_ + 1024);                           \
    GLL(sB_, dB_); GLL(sB_ + 16 * KDIM, dB_ + 1024);                           \
  } while (0)

template <int KDIM, bool GELU>
__global__ __launch_bounds__(256, 3) void k_gemm4(
    const unsigned short* __restrict__ Amat,  // [SLOTSP][KDIM] bf16
    const unsigned short* __restrict__ W,     // [EE][NTOT][KDIM] bf16
    const float* __restrict__ bias,           // [EE][NTOT]
    unsigned short* __restrict__ Outm,        // [SLOTSP][NTOT] bf16
    const int* __restrict__ ctrl, int NTOT) {
  constexpr int NT = KDIM / 32;
  __shared__ __align__(16) char smem[32768];
  const int* rtp = ctrl + 25;

  const int nwg = gridDim.x * gridDim.y;
  const int lin = blockIdx.y * gridDim.x + blockIdx.x;
  const int xcd = lin & 7, loc = lin >> 3;
  const int q = nwg >> 3, rr = nwg & 7;
  const int lin2 = (xcd < rr ? xcd * (q + 1) : rr * (q + 1) + (xcd - rr) * q) + loc;
  const int by = lin2 % gridDim.y;
  const int bx = lin2 / gridDim.y;
  if (bx >= rtp[EE]) return;
  int e = 0;
  while (bx >= rtp[e + 1]) ++e;
  const int rt = bx - rtp[e];
  const int row0 = ctrl[8 + e] + rt * 128;
  int vrows = ctrl[e] - rt * 128;
  if (vrows > 128) vrows = 128;
  const int n0 = by * 128;

  const int tid = threadIdx.x, lane = tid & 63, w = tid >> 6;
  const int wr = w >> 1, wc = w & 1;

  const int u = (lane * 16) ^ (((lane >> 5) & 1) << 5);
  const int ri = u >> 6;
  const int ci = (u & 63) >> 1;
  const unsigned short* pA = Amat + (size_t)(row0 + 32 * w + ri) * KDIM + ci;
  const unsigned short* pB = W + ((size_t)e * NTOT + n0 + 32 * w + ri) * KDIM + ci;
  char* sL = smem + (2 * w) * 1024 + lane * 16;

  const int lt = (((lane & 15) << 6) | ((lane >> 4) << 4)) ^ (((lane >> 3) & 1) << 5);

  f32x4 acc[4][4];
#pragma unroll
  for (int m = 0; m < 4; ++m)
#pragma unroll
    for (int n = 0; n < 4; ++n) acc[m][n] = (f32x4){0.f, 0.f, 0.f, 0.f};

  bf16x8 a[4], b[4];

  STAGE(0, 0);
  __syncthreads();

  for (int kt = 0; kt < NT; ++kt) {
    const int p = kt & 1;
    if (kt + 1 < NT) STAGE(p ^ 1, kt + 1);
    const char* ab = smem + p * 16384 + wr * 4096 + lt;
    const char* bb = smem + p * 16384 + 8192 + wc * 4096 + lt;
#pragma unroll
    for (int m = 0; m < 4; ++m) a[m] = *(const bf16x8*)(ab + m * 1024);
#pragma unroll
    for (int n = 0; n < 4; ++n) b[n] = *(const bf16x8*)(bb + n * 1024);
#pragma unroll
    for (int m = 0; m < 4; ++m)
#pragma unroll
      for (int n = 0; n < 4; ++n)
        acc[m][n] = MF(a[m], b[n], acc[m][n]);
    __syncthreads();
  }

#pragma unroll
  for (int m = 0; m < 4; ++m) {
    const int rbase = wr * 64 + m * 16 + (lane >> 4) * 4;
#pragma unroll
    for (int n = 0; n < 4; ++n) {
      const int col = n0 + wc * 64 + n * 16 + (lane & 15);
      const float bv_ = bias[(size_t)e * NTOT + col];
#pragma unroll
      for (int j = 0; j < 4; ++j) {
        const int r = rbase + j;
        if (r < vrows) {
          float vv = acc[m][n][j] + bv_;
          if constexpr (GELU) vv = 0.5f * vv * (1.0f + erff(vv * 0.70710678f));
          Outm[(size_t)(row0 + r) * NTOT + col] = f2bf(vv);
        }
      }
    }
  }
}

// -------------------- combine: out[t] = g0*Y[p0] + g1*Y[p1] --------------------
__global__ __launch_bounds__(256) void k_combine(
    const unsigned short* __restrict__ Y, const int* __restrict__ tok_pos,
    const float* __restrict__ gates, float* __restrict__ out) {
  int t = blockIdx.x, tid = threadIdx.x;
  int p0 = tok_pos[2 * t], p1 = tok_pos[2 * t + 1];
  float g0 = gates[2 * t], g1 = gates[2 * t + 1];
  ushort4 y0 = ((const ushort4*)(Y + (size_t)p0 * DD))[tid];
  ushort4 y1 = ((const ushort4*)(Y + (size_t)p1 * DD))[tid];
  float4 o;
  o.x = g0 * bf2f(y0.x) + g1 * bf2f(y1.x);
  o.y = g0 * bf2f(y0.y) + g1 * bf2f(y1.y);
  o.z = g0 * bf2f(y0.z) + g1 * bf2f(y1.z);
  o.w = g0 * bf2f(y0.w) + g1 * bf2f(y1.w);
  ((float4*)(out + (size_t)t * DD))[tid] = o;
}

__global__ __launch_bounds__(256) void k_sentinel(float* out, int n) {
  int i = blockIdx.x * 256 + threadIdx.x;
  if (i < n) out[i] = 12345.0f;
}

extern "C" void kernel_launch(void* const* d_in, const int* in_sizes, int n_in,
                              void* d_out, int out_size, void* d_ws, size_t ws_size,
                              hipStream_t stream) {
  const float* x   = (const float*)d_in[0];
  const float* rls = (const float*)d_in[1];
  const float* rlb = (const float*)d_in[2];
  const float* rw  = (const float*)d_in[3];
  const float* rb  = (const float*)d_in[4];
  const float* els = (const float*)d_in[5];
  const float* elb = (const float*)d_in[6];
  const float* w1  = (const float*)d_in[7];
  const float* b1  = (const float*)d_in[8];
  const float* w2  = (const float*)d_in[9];
  const float* b2  = (const float*)d_in[10];
  float* out = (float*)d_out;

  char* wsb = (char*)d_ws;
  size_t o = 0;
  int* ctrl = (int*)(wsb + o);                    o += 256;
  int* tok_pos = (int*)(wsb + o);                 o += (size_t)SLOTS * 4;
  float* gates = (float*)(wsb + o);               o += (size_t)SLOTS * 4;
  int* topk = (int*)(wsb + o);                    o += (size_t)TT * 4;
  int* ranks = (int*)(wsb + o);                   o += (size_t)SLOTS * 4;
  int* blkcnt = (int*)(wsb + o);                  o += (size_t)NRB * EE * 4;
  unsigned short* xhat = (unsigned short*)(wsb + o); o += (size_t)TT * DD * 2;
  unsigned short* Abuf = (unsigned short*)(wsb + o); o += (size_t)SLOTSP * DD * 2;
  unsigned short* w1b = (unsigned short*)(wsb + o);  o += (size_t)EE * HH * DD * 2;
  unsigned short* w2b = (unsigned short*)(wsb + o);  o += (size_t)EE * DD * HH * 2;
  unsigned short* Hm = (unsigned short*)(wsb + o);   o += (size_t)SLOTSP * HH * 2;
  unsigned short* Yb = (unsigned short*)(wsb + o);   o += (size_t)SLOTSP * DD * 2;

  if (ws_size < o) {
    k_sentinel<<<(out_size + 255) / 256, 256, 0, stream>>>(out, out_size);
    return;
  }

  k_fused_rw<<<NRB + NWB, 256, 0, stream>>>(x, rls, rlb, rw, rb, w1, w2, xhat,
                                            topk, gates, ranks, blkcnt, w1b, w2b);
  k_offsets<<<1, 256, 0, stream>>>(ctrl, blkcnt);
  k_build<<<SLOTS / 2, 256, 0, stream>>>(xhat, els, elb, ctrl, topk, ranks,
                                         blkcnt, Abuf, tok_pos);
  k_gemm4<DD, true><<<dim3(MAXRT1, HH / 128), 256, 0, stream>>>(Abuf, w1b, b1, Hm, ctrl, HH);
  k_gemm4<HH, false><<<dim3(MAXRT1, DD / 128), 256, 0, stream>>>(Hm, w2b, b2, Yb, ctrl, DD);
  k_combine<<<TT, 256, 0, stream>>>(Yb, tok_pos, gates, out);
}